// Round 5
// baseline (3415.239 us; speedup 1.0000x reference)
//
#include <hip/hip_runtime.h>

#define H_DIM 128
#define K_DIM 64
#define NSLICE 16
#define SLICE_F (K_DIM * H_DIM + K_DIM) /* 8256 floats: sums + counts */

// ---------------------------------------------------------------------------
// Kernel A: row-wise L2 normalize + per-community partial sums.
// One wave per row (grid-stride). lane l holds z[row][2l..2l+1].
// ---------------------------------------------------------------------------
__global__ __launch_bounds__(512) void k_norm_accum(
    const float* __restrict__ z, const int* __restrict__ comm,
    float* __restrict__ zn, float* __restrict__ wsums, int n) {
  __shared__ float lsum[K_DIM * H_DIM];  // 32 KB
  __shared__ float lcnt[K_DIM];
  const int tid = threadIdx.x;
  for (int i = tid; i < K_DIM * H_DIM; i += 512) lsum[i] = 0.f;
  if (tid < K_DIM) lcnt[tid] = 0.f;
  __syncthreads();

  const int lane = tid & 63;
  const int gw = (blockIdx.x * 512 + tid) >> 6;
  const int nw = (gridDim.x * 512) >> 6;
  for (int row = gw; row < n; row += nw) {
    const float2 v = ((const float2*)(z + (size_t)row * H_DIM))[lane];
    float ss = v.x * v.x + v.y * v.y;
#pragma unroll
    for (int m = 1; m < 64; m <<= 1) ss += __shfl_xor(ss, m, 64);
    const float rn = 1.f / sqrtf(ss);
    const float zx = v.x * rn, zy = v.y * rn;
    ((float2*)(zn + (size_t)row * H_DIM))[lane] = make_float2(zx, zy);
    // community id is wave-uniform: broadcast load + hoist to SGPR
    const int cid = __builtin_amdgcn_readfirstlane(comm[row]);
    atomicAdd(&lsum[cid * H_DIM + 2 * lane], zx);      // ds_add_f32
    atomicAdd(&lsum[cid * H_DIM + 2 * lane + 1], zy);  // ds_add_f32
    if (lane == 0) atomicAdd(&lcnt[cid], 1.f);
  }
  __syncthreads();

  // flush block partials into one of NSLICE global accumulator slices
  float* dst = wsums + (size_t)(blockIdx.x & (NSLICE - 1)) * SLICE_F;
  for (int i = tid; i < K_DIM * H_DIM; i += 512) {
    const float v = lsum[i];
    if (v != 0.f) unsafeAtomicAdd(&dst[i], v);  // global_atomic_add_f32
  }
  if (tid < K_DIM) unsafeAtomicAdd(&dst[K_DIM * H_DIM + tid], lcnt[tid]);
}

// ---------------------------------------------------------------------------
// Kernel B: reduce slices -> mu (d_out) and muT (ws, [H][K] for kernel C).
// ---------------------------------------------------------------------------
__global__ __launch_bounds__(256) void k_mu(
    const float* __restrict__ wsums, float* __restrict__ mu_out,
    float* __restrict__ muT) {
  const int f = blockIdx.x * 256 + threadIdx.x;  // 0..8191
  if (f >= K_DIM * H_DIM) return;
  const int k = f >> 7, h = f & (H_DIM - 1);
  float s = 0.f, c = 0.f;
#pragma unroll
  for (int sl = 0; sl < NSLICE; ++sl) {
    s += wsums[sl * SLICE_F + f];
    c += wsums[sl * SLICE_F + K_DIM * H_DIM + k];
  }
  const float m = s / c;
  mu_out[f] = m;
  muT[h * K_DIM + k] = m;
}

// ---------------------------------------------------------------------------
// Kernel C: dist = zn @ mu^T, r = softmax(30*dist).
// lane = community k (K==64==wave size). mu row lives in 128 VGPRs per lane
// (static-indexed, fully unrolled -> zero LDS in the main loop).
// zn rows fed via same-address float4 broadcast loads (1 L1 txn each).
// ---------------------------------------------------------------------------
__global__ __launch_bounds__(256) void k_dist_softmax(
    const float* __restrict__ zn, const float* __restrict__ muT,
    float* __restrict__ r_out, float* __restrict__ dist_out, int n) {
  const int lane = threadIdx.x & 63;
  const int gw = (blockIdx.x * 256 + threadIdx.x) >> 6;
  const int nw = (gridDim.x * 256) >> 6;

  float mur[H_DIM];  // mu[lane][0..127] in registers
#pragma unroll
  for (int j = 0; j < H_DIM; ++j) mur[j] = muT[j * K_DIM + lane];

  for (int row0 = gw * 2; row0 < n; row0 += nw * 2) {
    const int row1 = row0 + 1;
    const float4* a4 = (const float4*)(zn + (size_t)row0 * H_DIM);
    const float4* b4 = (const float4*)(zn + (size_t)row1 * H_DIM);
    float acc0 = 0.f, acc1 = 0.f;
#pragma unroll
    for (int j = 0; j < 32; ++j) {
      const float4 a = a4[j];
      const float4 b = b4[j];
      acc0 = fmaf(a.x, mur[4 * j + 0], acc0);
      acc0 = fmaf(a.y, mur[4 * j + 1], acc0);
      acc0 = fmaf(a.z, mur[4 * j + 2], acc0);
      acc0 = fmaf(a.w, mur[4 * j + 3], acc0);
      acc1 = fmaf(b.x, mur[4 * j + 0], acc1);
      acc1 = fmaf(b.y, mur[4 * j + 1], acc1);
      acc1 = fmaf(b.z, mur[4 * j + 2], acc1);
      acc1 = fmaf(b.w, mur[4 * j + 3], acc1);
    }
    const float t0 = 30.f * acc0, t1 = 30.f * acc1;
    float m0 = t0, m1 = t1;
#pragma unroll
    for (int m = 1; m < 64; m <<= 1) {
      m0 = fmaxf(m0, __shfl_xor(m0, m, 64));
      m1 = fmaxf(m1, __shfl_xor(m1, m, 64));
    }
    const float e0 = __expf(t0 - m0), e1 = __expf(t1 - m1);
    float s0 = e0, s1 = e1;
#pragma unroll
    for (int m = 1; m < 64; m <<= 1) {
      s0 += __shfl_xor(s0, m, 64);
      s1 += __shfl_xor(s1, m, 64);
    }
    dist_out[(size_t)row0 * K_DIM + lane] = acc0;
    r_out[(size_t)row0 * K_DIM + lane] = e0 / s0;
    if (row1 < n) {
      dist_out[(size_t)row1 * K_DIM + lane] = acc1;
      r_out[(size_t)row1 * K_DIM + lane] = e1 / s1;
    }
  }
}

// ---------------------------------------------------------------------------
extern "C" void kernel_launch(void* const* d_in, const int* in_sizes, int n_in,
                              void* d_out, int out_size, void* d_ws,
                              size_t ws_size, hipStream_t stream) {
  const float* z = (const float*)d_in[0];
  const int* comm = (const int*)d_in[1];
  const int n = in_sizes[1];  // N = number of rows (comm_ids count)

  float* out = (float*)d_out;
  float* zn = out;                               // [N,128]
  float* mu = zn + (size_t)n * H_DIM;            // [64,128]
  float* r = mu + K_DIM * H_DIM;                 // [N,64]
  float* dist = r + (size_t)n * K_DIM;           // [N,64]

  float* ws = (float*)d_ws;                      // NSLICE accumulator slices
  float* muT = ws + (size_t)NSLICE * SLICE_F;    // [128,64] transposed mu

  // ws is re-poisoned 0xAA before every timed call -> zero the slices
  hipMemsetAsync(ws, 0, (size_t)NSLICE * SLICE_F * sizeof(float), stream);

  k_norm_accum<<<512, 512, 0, stream>>>(z, comm, zn, ws, n);
  k_mu<<<(K_DIM * H_DIM + 255) / 256, 256, 0, stream>>>(ws, mu, muT);
  k_dist_softmax<<<2048, 256, 0, stream>>>(zn, muT, r, dist, n);
}